// Round 5
// baseline (4486.326 us; speedup 1.0000x reference)
//
#include <hip/hip_runtime.h>
#include <hip/hip_bf16.h>
#include <math.h>
#include <stddef.h>

namespace {

constexpr int V = 32000, H = 512, L = 4, A = 384, B = 2, T = 32, FF = 2048;
constexpr long LOGITS = (long)B * T * V;   // 2,048,000
constexpr int GRID = 256, NT = 512;
constexpr int XG = 4;                      // token groups per batch
constexpr int XK = 8;                      // blocks per x-group
constexpr int NGB = 8;                     // ghost blocks per (l,b)
constexpr float EPS = 1e-5f;

typedef short bf16x8 __attribute__((ext_vector_type(8)));
typedef float f32x4 __attribute__((ext_vector_type(4)));

struct WS {
  // ---- zeroed region ----
  unsigned gbar_cnt, gbar_gen;
  unsigned pad0[62];
  unsigned xcnt[B][XG][3];
  unsigned pad1[40];
  unsigned gcol_cnt[L][T][B];
  unsigned tok_flag[T][L][B];
  unsigned pad2[64];
  float gcol[L][T][B][H];          // atomicAdd accumulated
  // ---- not zeroed (fully written before read every launch) ----
  float asum[T][L][B][H];
  float uv[T][L][B][A + H];
  float outs[T][B][H];
  float lnouts[T * B][H];
  float xnext[B][XG][H];
  float hbuf[B][XG][FF];
  float initcol[L * B * H];
  uint4 bpk[L][2][2][16][32][64];  // bf16 frag-packed W: [l][mat g/t][split hi/lo][kt][ct][lane]
};

union __align__(16) SMem {
  struct { float s[16][516]; uint4 Ahi[16][64]; uint4 Alo[16][64]; } g;  // ~66 KB
  struct { float x[H], lnx[H], lnx2[H], xm[H], h[FF], red[8], bu[L]; } x;
  struct { float tile[125][64]; } hd;
};

__device__ __forceinline__ float dot4(const float4& a, const float4& b) {
  return a.x * b.x + a.y * b.y + a.z * b.z + a.w * b.w;
}
__device__ __forceinline__ unsigned bf16r(float f) {
  unsigned u = __float_as_uint(f);
  return (u + 0x7fffu + ((u >> 16) & 1u)) >> 16;
}
__device__ __forceinline__ float aload(const float* p) {
  return __hip_atomic_load(p, __ATOMIC_RELAXED, __HIP_MEMORY_SCOPE_AGENT);
}
__device__ __forceinline__ void astore(float* p, float v) {
  __hip_atomic_store(p, v, __ATOMIC_RELAXED, __HIP_MEMORY_SCOPE_AGENT);
}
__device__ __forceinline__ float wave_red(float v) {
  #pragma unroll
  for (int off = 1; off < 64; off <<= 1) v += __shfl_xor(v, off);
  return v;
}
__device__ __forceinline__ f32x4 mfma16(bf16x8 a, bf16x8 b, f32x4 c) {
  return __builtin_amdgcn_mfma_f32_16x16x32_bf16(a, b, c, 0, 0, 0);
}

__device__ void wait_u32(unsigned* p, unsigned target) {
  int spin = 0;
  while (__hip_atomic_load(p, __ATOMIC_RELAXED, __HIP_MEMORY_SCOPE_AGENT) < target) {
    __builtin_amdgcn_s_sleep(8);
    if ((++spin & 63) == 0)  // deadlock backstop (acquire refreshes caches)
      (void)__hip_atomic_load(p, __ATOMIC_ACQUIRE, __HIP_MEMORY_SCOPE_AGENT);
  }
}

__device__ void gbar(WS* ws) {
  __syncthreads();
  if (threadIdx.x == 0) {
    __threadfence();
    unsigned g = __hip_atomic_load(&ws->gbar_gen, __ATOMIC_RELAXED, __HIP_MEMORY_SCOPE_AGENT);
    unsigned a = __hip_atomic_fetch_add(&ws->gbar_cnt, 1u, __ATOMIC_ACQ_REL, __HIP_MEMORY_SCOPE_AGENT);
    if (a == (unsigned)(GRID - 1)) {
      __hip_atomic_store(&ws->gbar_cnt, 0u, __ATOMIC_RELAXED, __HIP_MEMORY_SCOPE_AGENT);
      __hip_atomic_fetch_add(&ws->gbar_gen, 1u, __ATOMIC_RELEASE, __HIP_MEMORY_SCOPE_AGENT);
    } else {
      wait_u32(&ws->gbar_gen, g + 1);
    }
    __threadfence();
  }
  __syncthreads();
}

__device__ void phase_done(unsigned* cnt) {
  __builtin_amdgcn_s_waitcnt(0);
  __syncthreads();
  if (threadIdx.x == 0)
    __hip_atomic_fetch_add(cnt, 1u, __ATOMIC_RELEASE, __HIP_MEMORY_SCOPE_AGENT);
}
__device__ void phase_wait(unsigned* cnt, unsigned tgt) {
  if (threadIdx.x == 0) wait_u32(cnt, tgt);
  __syncthreads();
}

__device__ float block_reduce(float v, SMem& sm) {
  v = wave_red(v);
  int wv = threadIdx.x >> 6;
  __syncthreads();
  if ((threadIdx.x & 63) == 0) sm.x.red[wv] = v;
  __syncthreads();
  float s = 0.f;
  #pragma unroll
  for (int q = 0; q < 8; ++q) s += sm.x.red[q];
  return s;
}

__device__ void ln512(SMem& sm, const float* in, float* outp,
                      const float* w, const float* b) {
  int tid = threadIdx.x;
  float xv = in[tid];
  float m = block_reduce(xv, sm) * (1.f / H);
  float d = xv - m;
  float var = block_reduce(d * d, sm) * (1.f / H);
  float inv = rsqrtf(var + EPS);
  outp[tid] = d * inv * w[tid] + b[tid];
  __syncthreads();
}

// ---------------------------------------------------------------- ghost (MFMA)
// Block owns 16 rows of one (l,b). State f32 in LDS; per rec: split state into
// bf16 hi/lo A-fragments, 3-product split MFMA vs frag-packed W, nonlinearity,
// in-place update, colsum publish every 2nd rec. Zero inter-block sync.
__device__ void ghost_mfma(int l, int b, int r0, WS* ws, SMem& sm,
                           const float* __restrict__ states, float* __restrict__ fs) {
  const int tid = threadIdx.x, wv = tid >> 6, lane = tid & 63;
  for (int i = tid; i < 16 * 512; i += NT) {
    int r = i >> 9, k = i & 511;
    sm.g.s[r][k] = states[((((long)l * B + b) * H) + A + r0 + r) * H + k];
  }
  __syncthreads();
  const int ct0 = wv * 4;

  for (int rec = 0; rec < 2 * T; ++rec) {
    // ---- stage A fragments (hi/lo split of current state) ----
    for (int q = tid; q < 1024; q += NT) {
      int kt = q >> 6, ln = q & 63;
      int row = ln & 15, kb = kt * 32 + ((ln >> 4) << 3);
      unsigned h[8], lo[8];
      #pragma unroll
      for (int j = 0; j < 8; ++j) {
        float v = sm.g.s[row][kb + j];
        h[j] = bf16r(v);
        float hf = __uint_as_float(h[j] << 16);
        lo[j] = bf16r(v - hf);
      }
      uint4 uh, ul;
      uh.x = h[0] | (h[1] << 16);  uh.y = h[2] | (h[3] << 16);
      uh.z = h[4] | (h[5] << 16);  uh.w = h[6] | (h[7] << 16);
      ul.x = lo[0] | (lo[1] << 16); ul.y = lo[2] | (lo[3] << 16);
      ul.z = lo[4] | (lo[5] << 16); ul.w = lo[6] | (lo[7] << 16);
      sm.g.Ahi[kt][ln] = uh;
      sm.g.Alo[kt][ln] = ul;
    }
    __syncthreads();

    f32x4 accg[4], acct[4];
    #pragma unroll
    for (int c = 0; c < 4; ++c) { accg[c] = {0.f, 0.f, 0.f, 0.f}; acct[c] = {0.f, 0.f, 0.f, 0.f}; }
    for (int kt = 0; kt < 16; ++kt) {
      bf16x8 ahi = __builtin_bit_cast(bf16x8, sm.g.Ahi[kt][lane]);
      bf16x8 alo = __builtin_bit_cast(bf16x8, sm.g.Alo[kt][lane]);
      #pragma unroll
      for (int c = 0; c < 4; ++c) {
        int ct = ct0 + c;
        bf16x8 bgh = __builtin_bit_cast(bf16x8, ws->bpk[l][0][0][kt][ct][lane]);
        bf16x8 bgl = __builtin_bit_cast(bf16x8, ws->bpk[l][0][1][kt][ct][lane]);
        bf16x8 bth = __builtin_bit_cast(bf16x8, ws->bpk[l][1][0][kt][ct][lane]);
        bf16x8 btl = __builtin_bit_cast(bf16x8, ws->bpk[l][1][1][kt][ct][lane]);
        accg[c] = mfma16(ahi, bgh, accg[c]);
        accg[c] = mfma16(ahi, bgl, accg[c]);
        accg[c] = mfma16(alo, bgh, accg[c]);
        acct[c] = mfma16(ahi, bth, acct[c]);
        acct[c] = mfma16(ahi, btl, acct[c]);
        acct[c] = mfma16(alo, bth, acct[c]);
      }
    }

    const int t = rec >> 1;
    const bool pub = (rec & 1) != 0;
    const int rb = (lane >> 4) * 4;      // D: row = 4*(lane>>4)+reg, col = ct*16 + (lane&15)
    #pragma unroll
    for (int c = 0; c < 4; ++c) {
      int col = (ct0 + c) * 16 + (lane & 15);
      float cs = 0.f;
      #pragma unroll
      for (int r = 0; r < 4; ++r) {
        float sig = 1.f / (1.f + expf(-accg[c][r]));
        float th = tanhf(acct[c][r]);
        float nv = sm.g.s[rb + r][col] + sig * th;
        sm.g.s[rb + r][col] = nv;
        cs += nv;
      }
      if (pub) {
        cs += __shfl_xor(cs, 16);
        cs += __shfl_xor(cs, 32);
        if (lane < 16)
          __hip_atomic_fetch_add(&ws->gcol[l][t][b][col], cs,
                                 __ATOMIC_RELAXED, __HIP_MEMORY_SCOPE_AGENT);
      }
    }
    if (pub) {
      __builtin_amdgcn_s_waitcnt(0);
      __syncthreads();
      if (tid == 0)
        __hip_atomic_fetch_add(&ws->gcol_cnt[l][t][b], 1u,
                               __ATOMIC_RELEASE, __HIP_MEMORY_SCOPE_AGENT);
    } else {
      __syncthreads();
    }
  }
  for (int i = tid; i < 16 * 512; i += NT) {
    int r = i >> 9, k = i & 511;
    fs[((((long)l * B + b) * H) + A + r0 + r) * H + k] = sm.g.s[r][k];
  }
}

// ---------------------------------------------------------------- x-group (8-block coop)
__device__ void x_group(int b, int g, int role, WS* ws, SMem& sm,
                        const int* ids, const float* emb,
                        const float* nx_w, const float* nx_b,
                        const float* Wp, const float* bp,
                        const float* ns_w, const float* ns_b,
                        const float* W1, const float* b1,
                        const float* W2, const float* b2) {
  const int tid = threadIdx.x, wv = tid >> 6, lane = tid & 63;
  if (tid < L) {
    float s = 0.f;
    for (int i = 0; i < A; ++i) s += bp[(long)tid * (A + H) + i];
    sm.x.bu[tid] = s;
  }
  __syncthreads();
  unsigned* c0 = &ws->xcnt[b][g][0];
  unsigned* c1 = &ws->xcnt[b][g][1];
  unsigned* c2 = &ws->xcnt[b][g][2];

  for (int gs = 0; gs < (T / XG) * L; ++gs) {
    const int tloc = gs >> 2, l = gs & 3, t = g + XG * tloc;
    const long wb = (long)l * (A + H);
    // ---------------- P1: get x, LN1, Wp-slice ----------------
    if (l == 0) {
      sm.x.x[tid] = emb[(long)ids[b * T + t] * H + tid];
    } else {
      phase_wait(c2, (unsigned)(XK * gs));
      sm.x.x[tid] = aload(&ws->xnext[b][g][tid]);
    }
    __syncthreads();
    ln512(sm, sm.x.x, sm.x.lnx, nx_w + l * H, nx_b + l * H);
    {
      float xr[8];
      #pragma unroll
      for (int q = 0; q < 8; ++q) xr[q] = sm.x.lnx[lane + 64 * q];
      for (int i = 0; i < 14; i += 2) {
        int o0 = role * 112 + wv * 14 + i;
        const float* w0 = Wp + (wb + o0) * H + lane;
        const float* w1 = Wp + (wb + o0 + 1) * H + lane;
        float p0 = 0.f, p1 = 0.f;
        #pragma unroll
        for (int q = 0; q < 8; ++q) {
          p0 = fmaf(xr[q], w0[64 * q], p0);
          p1 = fmaf(xr[q], w1[64 * q], p1);
        }
        p0 = wave_red(p0); p1 = wave_red(p1);
        if (lane == 0) {
          astore(&ws->uv[t][l][b][o0], p0 + bp[wb + o0]);
          astore(&ws->uv[t][l][b][o0 + 1], p1 + bp[wb + o0 + 1]);
        }
      }
    }
    phase_done(c0);
    phase_wait(c0, (unsigned)(XK * (gs + 1)));
    // ---------------- P2: U1, asum chain, xm, LN2, W1-slice ----------------
    float uu = (tid < A) ? aload(&ws->uv[t][l][b][tid]) : 0.f;
    float U1 = block_reduce(uu, sm);
    float vt = aload(&ws->uv[t][l][b][A + tid]);
    if (t > 0) {
      if (tid == 0) wait_u32(&ws->tok_flag[t - 1][l][b], 1u);
      __syncthreads();
    }
    float aprev = (t > 0) ? aload(&ws->asum[t - 1][l][b][tid]) : 0.f;
    float anew = aprev + U1 * vt;
    if (role == 0) {
      astore(&ws->asum[t][l][b][tid], anew);
      __builtin_amdgcn_s_waitcnt(0);
      __syncthreads();
      if (tid == 0)
        __hip_atomic_store(&ws->tok_flag[t][l][b], 1u, __ATOMIC_RELEASE, __HIP_MEMORY_SCOPE_AGENT);
    }
    if (tid == 0) wait_u32(&ws->gcol_cnt[l][t][b], (unsigned)NGB);
    __syncthreads();
    float gc = aload(&ws->gcol[l][t][b][tid]);
    sm.x.xm[tid] = sm.x.x[tid] +
                   (anew + ws->initcol[(l * B + b) * H + tid] +
                    (float)(t + 1) * sm.x.bu[l] * bp[wb + A + tid] + gc) * (1.f / H);
    __syncthreads();
    ln512(sm, sm.x.xm, sm.x.lnx2, ns_w + l * H, ns_b + l * H);
    {
      float xr[8];
      #pragma unroll
      for (int q = 0; q < 8; ++q) xr[q] = sm.x.lnx2[lane + 64 * q];
      for (int i = 0; i < 32; i += 4) {
        int ob = role * 256 + wv * 32 + i;
        float p0 = 0.f, p1 = 0.f, p2 = 0.f, p3 = 0.f;
        const float* w0 = W1 + ((long)l * FF + ob) * H + lane;
        const float* w1 = w0 + H;
        const float* w2 = w1 + H;
        const float* w3 = w2 + H;
        #pragma unroll
        for (int q = 0; q < 8; ++q) {
          p0 = fmaf(xr[q], w0[64 * q], p0);
          p1 = fmaf(xr[q], w1[64 * q], p1);
          p2 = fmaf(xr[q], w2[64 * q], p2);
          p3 = fmaf(xr[q], w3[64 * q], p3);
        }
        p0 = wave_red(p0); p1 = wave_red(p1); p2 = wave_red(p2); p3 = wave_red(p3);
        if (lane == 0) {
          #pragma unroll
          for (int j = 0; j < 4; ++j) {
            float pv = (j == 0) ? p0 : (j == 1) ? p1 : (j == 2) ? p2 : p3;
            float z = pv + b1[(long)l * FF + ob + j];
            astore(&ws->hbuf[b][g][ob + j], 0.5f * z * (1.f + erff(z * 0.70710678118f)));
          }
        }
      }
    }
    phase_done(c1);
    phase_wait(c1, (unsigned)(XK * (gs + 1)));
    // ---------------- P3: W2-slice + residual ----------------
    for (int i = tid; i < FF; i += NT) sm.x.h[i] = aload(&ws->hbuf[b][g][i]);
    __syncthreads();
    {
      float hr[32];
      #pragma unroll
      for (int q = 0; q < 32; ++q) hr[q] = sm.x.h[lane + 64 * q];
      for (int i = 0; i < 8; i += 4) {
        int ob = role * 64 + wv * 8 + i;
        float p0 = 0.f, p1 = 0.f, p2 = 0.f, p3 = 0.f;
        const float* w0 = W2 + ((long)l * H + ob) * FF + lane;
        const float* w1 = w0 + FF;
        const float* w2 = w1 + FF;
        const float* w3 = w2 + FF;
        #pragma unroll
        for (int q = 0; q < 32; ++q) {
          p0 = fmaf(hr[q], w0[64 * q], p0);
          p1 = fmaf(hr[q], w1[64 * q], p1);
          p2 = fmaf(hr[q], w2[64 * q], p2);
          p3 = fmaf(hr[q], w3[64 * q], p3);
        }
        p0 = wave_red(p0); p1 = wave_red(p1); p2 = wave_red(p2); p3 = wave_red(p3);
        if (lane == 0) {
          #pragma unroll
          for (int j = 0; j < 4; ++j) {
            float pv = (j == 0) ? p0 : (j == 1) ? p1 : (j == 2) ? p2 : p3;
            int o = ob + j;
            float xo = sm.x.xm[o] + pv + b2[(long)l * H + o];
            if (l == L - 1) astore(&ws->outs[t][b][o], xo);
            else            astore(&ws->xnext[b][g][o], xo);
          }
        }
      }
    }
    phase_done(c2);
  }
}

// ---------------------------------------------------------------- prologue pack
__global__ __launch_bounds__(256) void pack_kernel(const float* __restrict__ Wg,
                                                   const float* __restrict__ Wt,
                                                   const float* __restrict__ states,
                                                   WS* ws) {
  const int bid = blockIdx.x, tid = threadIdx.x;
  if (bid < 1024) {
    #pragma unroll
    for (int rep = 0; rep < 2; ++rep) {
      unsigned f = (unsigned)bid * 512u + (unsigned)rep * 256u + (unsigned)tid;
      int lane = f & 63, ct = (f >> 6) & 31, kt = (f >> 11) & 15;
      int split = (f >> 15) & 1, mat = (f >> 16) & 1, l = f >> 17;
      int o = ct * 16 + (lane & 15), kb = kt * 32 + ((lane >> 4) << 3);
      const float* src = (mat ? Wt : Wg) + ((long)l * H + o) * H + kb;
      unsigned v8[8];
      #pragma unroll
      for (int j = 0; j < 8; ++j) {
        float w = src[j];
        unsigned h = bf16r(w);
        if (split) {
          float hf = __uint_as_float(h << 16);
          h = bf16r(w - hf);
        }
        v8[j] = h;
      }
      uint4 u;
      u.x = v8[0] | (v8[1] << 16); u.y = v8[2] | (v8[3] << 16);
      u.z = v8[4] | (v8[5] << 16); u.w = v8[6] | (v8[7] << 16);
      ws->bpk[l][mat][split][kt][ct][lane] = u;
    }
  } else if (bid < 1032) {
    int lb = bid - 1024, l = lb >> 1, b = lb & 1;
    #pragma unroll
    for (int half = 0; half < 2; ++half) {
      int col = tid + half * 256;
      float acc = 0.f;
      for (int i = 0; i < A; ++i)
        acc += states[(((long)l * B + b) * H + i) * H + col];
      ws->initcol[(l * B + b) * H + col] = acc;
    }
  }
}

// ---------------------------------------------------------------- main kernel
__global__ __launch_bounds__(NT, 1) void vega_kernel(
    const int* __restrict__ ids, const float* __restrict__ states,
    const float* __restrict__ emb,
    const float* __restrict__ nx_w, const float* __restrict__ nx_b,
    const float* __restrict__ Wp, const float* __restrict__ bp,
    const float* __restrict__ ns_w, const float* __restrict__ ns_b,
    const float* __restrict__ W1, const float* __restrict__ b1,
    const float* __restrict__ W2, const float* __restrict__ b2,
    const float* __restrict__ on_w, const float* __restrict__ on_b,
    const float* __restrict__ head_W, const float* __restrict__ head_b,
    float* __restrict__ out, WS* ws) {
  __shared__ SMem sm;
  const int bid = blockIdx.x, tid = threadIdx.x;
  float* fs = out + LOGITS;

  const int c = bid & 7, j = bid >> 3;
  if (c < 4) {
    // ghost on XCDs 0-3: layer c, 16 blocks (2 b x 8 row-tiles)
    if (j < 16) ghost_mfma(c, j >> 3, (j & 7) * 16, ws, sm, states, fs);
  } else {
    // x-pipeline on XCDs 4-7: role pinned per XCD (same weight slices share L2)
    if (j < 16) {
      int role = (c - 4) + 4 * (j & 1);
      int grp = j >> 1, b = grp >> 2, g = grp & 3;
      x_group(b, g, role, ws, sm, ids, emb, nx_w, nx_b, Wp, bp,
              ns_w, ns_b, W1, b1, W2, b2);
    }
  }

  gbar(ws);

  // -------- E1: active fstates reconstruction + final LN of outs --------
  if (bid < 192) {
    int lb = bid / 24, sub = bid % 24;
    int l = lb >> 1, b = lb & 1, r0 = sub * 16;
    long base = (long)l * (A + H);
    float bv = bp[base + A + tid];
    float acc[16];
    #pragma unroll
    for (int q = 0; q < 16; ++q) acc[q] = 32.f * bp[base + r0 + q] * bv;
    for (int t2 = 0; t2 < T; ++t2) {
      float vv = ws->uv[t2][l][b][A + tid];
      const float* u = &ws->uv[t2][l][b][0];
      #pragma unroll
      for (int q = 0; q < 16; ++q) acc[q] = fmaf(u[r0 + q], vv, acc[q]);
    }
    #pragma unroll
    for (int q = 0; q < 16; ++q)
      fs[(((long)l * B + b) * H + (r0 + q)) * H + tid] =
          states[(((long)l * B + b) * H + (r0 + q)) * H + tid] + acc[q];
  }
  if (bid < T * B) {
    int row = bid, t = row >> 1, b = row & 1;
    ln512(sm, ws->outs[t][b], ws->lnouts[row], on_w, on_b);
  }

  gbar(ws);

  // -------- E2: head GEMM (64 rows x 125 vocab per block, K=512) --------
  {
    const int wv = tid >> 6, lane = tid & 63;
    const long vbase = (long)bid * 125;
    float acc[16];
    #pragma unroll
    for (int q = 0; q < 16; ++q) acc[q] = 0.f;
    for (int cc = 0; cc < 8; ++cc) {
      float4 xr[16];
      #pragma unroll
      for (int q = 0; q < 16; ++q)
        xr[q] = *(const float4*)&ws->lnouts[lane][cc * 64 + q * 4];
      #pragma unroll
      for (int vi = 0; vi < 16; ++vi) {
        int vloc = vi * 8 + wv;
        if (vloc < 125) {
          const float4* wp_ = (const float4*)(head_W + (vbase + vloc) * H + cc * 64);
          float s = 0.f;
          #pragma unroll
          for (int q = 0; q < 16; ++q) s += dot4(xr[q], wp_[q]);
          acc[vi] += s;
        }
      }
    }
    #pragma unroll
    for (int vi = 0; vi < 16; ++vi) {
      int vloc = vi * 8 + wv;
      if (vloc < 125) sm.hd.tile[vloc][lane] = acc[vi] + head_b[vbase + vloc];
    }
    __syncthreads();
    for (int idx = tid; idx < 64 * 125; idx += NT) {
      int row = idx / 125, vl = idx % 125;
      int t = row >> 1, b = row & 1;
      out[((long)(b * T + t)) * V + vbase + vl] = sm.hd.tile[vl][row];
    }
  }
}

}  // namespace

extern "C" void kernel_launch(void* const* d_in, const int* in_sizes, int n_in,
                              void* d_out, int out_size, void* d_ws, size_t ws_size,
                              hipStream_t stream) {
  (void)in_sizes; (void)n_in; (void)out_size; (void)ws_size;
  const int*   ids    = (const int*)d_in[0];
  const float* states = (const float*)d_in[1];
  const float* emb    = (const float*)d_in[2];
  const float* nx_w   = (const float*)d_in[3];
  const float* nx_b   = (const float*)d_in[4];
  const float* Wp     = (const float*)d_in[5];
  const float* bp     = (const float*)d_in[6];
  const float* Wg     = (const float*)d_in[7];
  const float* Wt     = (const float*)d_in[8];
  const float* ns_w   = (const float*)d_in[9];
  const float* ns_b   = (const float*)d_in[10];
  const float* W1     = (const float*)d_in[11];
  const float* b1     = (const float*)d_in[12];
  const float* W2     = (const float*)d_in[13];
  const float* b2     = (const float*)d_in[14];
  const float* on_w   = (const float*)d_in[15];
  const float* on_b   = (const float*)d_in[16];
  const float* head_W = (const float*)d_in[17];
  const float* head_b = (const float*)d_in[18];
  float* out = (float*)d_out;
  WS* ws = (WS*)d_ws;

  hipMemsetAsync(d_ws, 0, offsetof(WS, asum), stream);
  pack_kernel<<<dim3(1032), dim3(256), 0, stream>>>(Wg, Wt, states, ws);
  vega_kernel<<<dim3(GRID), dim3(NT), 0, stream>>>(
      ids, states, emb, nx_w, nx_b, Wp, bp, ns_w, ns_b,
      W1, b1, W2, b2, on_w, on_b, head_W, head_b, out, ws);
}